// Round 12
// baseline (212.681 us; speedup 1.0000x reference)
//
#include <hip/hip_runtime.h>

typedef unsigned int uint;

#define N_NODES 50000
#define N_EDGES 1600000
#define DIM 128
#define LN_EPS 1e-10f

#define ROWS_PER_GROUP 32
#define N_GROUPS 1563            // ceil(50000/32)
#define EPB 8192                 // edges per scatter block
#define SB 196                   // scatter blocks (196*8192 >= 1.6M)
#define CAPR 76                  // per-row agg list slots (mean 32, +11 sigma)

__device__ __forceinline__ uint f2bf(float x) {
    uint u = __float_as_uint(x);
    return (u + 0x7FFFu + ((u >> 16) & 1u)) >> 16;   // RNE to bf16
}

// ---------------------------------------------------------------------------
// convert_pack: feat fp32 -> packed bf16 + W pack (last block).  Zero LDS.
// ---------------------------------------------------------------------------
__global__ __launch_bounds__(256) void convert_pack(
    const float* __restrict__ feat, const float* __restrict__ W,
    uint* __restrict__ featb_u, uint* __restrict__ wpk_u)
{
    const int b = blockIdx.x;
    const int t = threadIdx.x;
    if (b < 3125) {                     // 1.6M float4, 512 per block
        int i = b * 512 + t;
        float4 v0 = ((const float4*)feat)[i];
        float4 v1 = ((const float4*)feat)[i + 256];
        ((uint2*)featb_u)[i] = make_uint2(
            f2bf(v0.x) | (f2bf(v0.y) << 16), f2bf(v0.z) | (f2bf(v0.w) << 16));
        ((uint2*)featb_u)[i + 256] = make_uint2(
            f2bf(v1.x) | (f2bf(v1.y) << 16), f2bf(v1.z) | (f2bf(v1.w) << 16));
    } else {                            // W pack
        for (int idx = t; idx < 8192; idx += 256) {
            int g = idx >> 8, rem = idx & 255;
            int l = rem >> 2, k = rem & 3, i = 4 * g + k;
            wpk_u[idx] = f2bf(W[l * DIM + i]) |
                         (f2bf(W[(l + 64) * DIM + i]) << 16);
        }
    }
}

// ---------------------------------------------------------------------------
// scatter v5: R11 post-mortem showed the wall is HBM partial-line write-
// through: destination-clustered runs are only ~5 entries (42 B) at random
// offsets -> 306K partial 64-B lines, ~8x write amplification (same as R2's
// 101 MB).  Fix: each block writes its group-SORTED entries to its OWN
// contiguous perm segment [bx*EPB ..) -- pure full-line streaming -- plus a
// (base|cnt<<16) table per (block,group).  NO global atomics (memset dies).
// Entry: col(0..15) | row_local(16..20), val.
// ---------------------------------------------------------------------------
__global__ __launch_bounds__(1024) void scatter(
    const int* __restrict__ rows, const int* __restrict__ cols,
    const float* __restrict__ vals, int2* __restrict__ perm,
    uint* __restrict__ tab)
{
    __shared__ int  cnt[N_GROUPS];
    __shared__ int  lcur[N_GROUPS];     // starts at local base; lbase = lcur-cnt
    __shared__ int  csum[128];
    __shared__ int  stash[EPB];         // 32 KB rows
    __shared__ int2 stageE[EPB];        // 64 KB
    const int bx = blockIdx.x;
    const int t  = threadIdx.x;

    for (int i = t; i < N_GROUPS; i += 1024) cnt[i] = 0;
    __syncthreads();

    // ---- phase A: load rows once, stash + histogram ----
    const int base = bx * EPB;
    for (int k = 0; k < EPB; k += 1024) {
        int e = base + k + t;
        int r = (e < N_EDGES) ? rows[e] : -1;
        stash[k + t] = r;
        if (r >= 0) atomicAdd(&cnt[r >> 5], 1);
    }
    __syncthreads();

    // ---- phase B: exclusive scan of cnt (128 chunks x 13, Hillis-Steele) ----
    if (t < 128) {
        int s = 0;
        for (int j = 0; j < 13; ++j) {
            int idx = t * 13 + j;
            if (idx < N_GROUPS) s += cnt[idx];
        }
        csum[t] = s;
    }
    __syncthreads();
    for (int off = 1; off < 128; off <<= 1) {
        int v = 0;
        if (t < 128) {
            v = csum[t];
            if (t >= off) v += csum[t - off];
        }
        __syncthreads();
        if (t < 128) csum[t] = v;
        __syncthreads();
    }
    if (t < 128) {
        int run = (t == 0) ? 0 : csum[t - 1];
        for (int j = 0; j < 13; ++j) {
            int idx = t * 13 + j;
            if (idx < N_GROUPS) { lcur[idx] = run; run += cnt[idx]; }
        }
    }
    __syncthreads();

    // ---- phase C: stage entries grouped by group id ----
    for (int k = 0; k < EPB; k += 1024) {
        int e = base + k + t;
        int r = stash[k + t];
        if (r >= 0) {
            int g = r >> 5;
            int pos = atomicAdd(&lcur[g], 1);
            stageE[pos] = make_int2(
                (uint)cols[e] | ((uint)(r & 31) << 16),
                __float_as_int(vals[e]));
        }
    }
    __syncthreads();

    // ---- phase D: table + full-line contiguous flush ----
    for (int g = t; g < N_GROUPS; g += 1024) {
        uint c  = (uint)cnt[g];
        uint lb = (uint)lcur[g] - c;
        tab[(size_t)bx * N_GROUPS + g] = lb | (c << 16);
    }
    int total = lcur[N_GROUPS - 1];     // == valid edges this block
    for (int k = 0; k < EPB; k += 1024) {
        int j = k + t;
        if (j < total)
            perm[(size_t)bx * EPB + j] = stageE[j];
    }
}

// ---------------------------------------------------------------------------
// agg_fused: one block per 32-row group (1563 blocks, 512 thr).
// Phase 1: walk the 196 (block,group) runs via tab, compact into 32 per-row
// LDS lists.  Phase 2: 4 rows/wave, bf16 gathers, unroll-8 ILP, fp32 reg
// accumulators.  Phase 3: rows -> LDS (overlaying dead lists).  Phase 4:
// 128x128 linear with packed-bf16 W from global (L2-hot) + ReLU + LN -> out.
// LDS 19.7 KB -> 4 blocks/CU = 32 waves/CU.
// ---------------------------------------------------------------------------
__global__ __launch_bounds__(512, 8) void agg_fused(
    const int2* __restrict__ perm, const uint* __restrict__ tab,
    const unsigned short* __restrict__ featb, const uint4* __restrict__ wpk,
    const float* __restrict__ bias, const float* __restrict__ scale,
    const float* __restrict__ offset, float* __restrict__ out)
{
    __shared__ int2 lists[32 * CAPR];    // 19456 B; rowsbuf (16 KB) overlays
    __shared__ int  lcnt[32];

    const int t = threadIdx.x;
    float* rowsbuf = (float*)lists;

    const int b = blockIdx.x;            // group id
    if (t < 32) lcnt[t] = 0;
    __syncthreads();

    for (int bi = t; bi < SB; bi += 512) {
        uint tv = tab[(size_t)bi * N_GROUPS + b];
        int lb = tv & 0xFFFF;
        int c  = tv >> 16;
        const int2* src = perm + (size_t)bi * EPB + lb;
        for (int k = 0; k < c; ++k) {
            int2 p = src[k];
            int rl = (p.x >> 16) & 31;
            int pos = atomicAdd(&lcnt[rl], 1);
            if (pos < CAPR)
                lists[rl * CAPR + pos] = make_int2(p.x & 0xFFFF, p.y);
        }
    }
    __syncthreads();

    const int lane = t & 63;
    const int wid  = t >> 6;        // 0..7
    const int rb   = wid * 4;       // first local row of this wave

    float ax[4], ay[4];
    #pragma unroll
    for (int j = 0; j < 4; ++j) {
        int rl = rb + j;
        int cnt = lcnt[rl];
        if (cnt > CAPR) cnt = CAPR;
        const int2* L = &lists[rl * CAPR];
        float sx = 0.f, sy = 0.f;
        int e = 0;
        for (; e + 7 < cnt; e += 8) {
            int2 p[8]; uint g[8];
            #pragma unroll
            for (int k = 0; k < 8; ++k) p[k] = L[e + k];
            #pragma unroll
            for (int k = 0; k < 8; ++k)
                g[k] = ((const uint*)(featb + (size_t)p[k].x * DIM))[lane];
            #pragma unroll
            for (int k = 0; k < 8; ++k) {
                float v = __int_as_float(p[k].y);
                sx = fmaf(v, __uint_as_float(g[k] << 16), sx);
                sy = fmaf(v, __uint_as_float(g[k] & 0xFFFF0000u), sy);
            }
        }
        for (; e < cnt; ++e) {
            int2 p = L[e];
            uint g = ((const uint*)(featb + (size_t)p.x * DIM))[lane];
            float v = __int_as_float(p.y);
            sx = fmaf(v, __uint_as_float(g << 16), sx);
            sy = fmaf(v, __uint_as_float(g & 0xFFFF0000u), sy);
        }
        ax[j] = sx; ay[j] = sy;
    }
    __syncthreads();               // lists dead -> reuse as rowsbuf

    #pragma unroll
    for (int j = 0; j < 4; ++j)
        ((float2*)rowsbuf)[(rb + j) * 64 + lane] = make_float2(ax[j], ay[j]);
    __syncthreads();

    // ---- phase 4: linear + ReLU + LN for this wave's 4 rows ----
    const float bb0 = bias[lane],   bb1 = bias[lane + 64];
    const float sc0 = scale[lane],  sc1 = scale[lane + 64];
    const float of0 = offset[lane], of1 = offset[lane + 64];

    const float4* R0 = (const float4*)(rowsbuf + (rb + 0) * DIM);
    const float4* R1 = (const float4*)(rowsbuf + (rb + 1) * DIM);
    const float4* R2 = (const float4*)(rowsbuf + (rb + 2) * DIM);
    const float4* R3 = (const float4*)(rowsbuf + (rb + 3) * DIM);

    float x0 = bb0, y0 = bb1, x1 = bb0, y1 = bb1;
    float x2 = bb0, y2 = bb1, x3 = bb0, y3 = bb1;

    #pragma unroll 4
    for (int g = 0; g < 32; ++g) {
        uint4 wv = wpk[g * 64 + lane];     // global read, L2-hot 64 KB
        float4 a0 = R0[g], a1 = R1[g], a2 = R2[g], a3 = R3[g];
        float w0, w1;
        w0 = __uint_as_float(wv.x << 16); w1 = __uint_as_float(wv.x & 0xFFFF0000u);
        x0 = fmaf(a0.x, w0, x0);  y0 = fmaf(a0.x, w1, y0);
        x1 = fmaf(a1.x, w0, x1);  y1 = fmaf(a1.x, w1, y1);
        x2 = fmaf(a2.x, w0, x2);  y2 = fmaf(a2.x, w1, y2);
        x3 = fmaf(a3.x, w0, x3);  y3 = fmaf(a3.x, w1, y3);
        w0 = __uint_as_float(wv.y << 16); w1 = __uint_as_float(wv.y & 0xFFFF0000u);
        x0 = fmaf(a0.y, w0, x0);  y0 = fmaf(a0.y, w1, y0);
        x1 = fmaf(a1.y, w0, x1);  y1 = fmaf(a1.y, w1, y1);
        x2 = fmaf(a2.y, w0, x2);  y2 = fmaf(a2.y, w1, y2);
        x3 = fmaf(a3.y, w0, x3);  y3 = fmaf(a3.y, w1, y3);
        w0 = __uint_as_float(wv.z << 16); w1 = __uint_as_float(wv.z & 0xFFFF0000u);
        x0 = fmaf(a0.z, w0, x0);  y0 = fmaf(a0.z, w1, y0);
        x1 = fmaf(a1.z, w0, x1);  y1 = fmaf(a1.z, w1, y1);
        x2 = fmaf(a2.z, w0, x2);  y2 = fmaf(a2.z, w1, y2);
        x3 = fmaf(a3.z, w0, x3);  y3 = fmaf(a3.z, w1, y3);
        w0 = __uint_as_float(wv.w << 16); w1 = __uint_as_float(wv.w & 0xFFFF0000u);
        x0 = fmaf(a0.w, w0, x0);  y0 = fmaf(a0.w, w1, y0);
        x1 = fmaf(a1.w, w0, x1);  y1 = fmaf(a1.w, w1, y1);
        x2 = fmaf(a2.w, w0, x2);  y2 = fmaf(a2.w, w1, y2);
        x3 = fmaf(a3.w, w0, x3);  y3 = fmaf(a3.w, w1, y3);
    }

    #pragma unroll
    for (int j = 0; j < 4; ++j) {
        int r = b * ROWS_PER_GROUP + rb + j;
        if (r >= N_NODES) continue;                       // wave-uniform
        float A0 = (j == 0) ? x0 : (j == 1) ? x1 : (j == 2) ? x2 : x3;
        float A1 = (j == 0) ? y0 : (j == 1) ? y1 : (j == 2) ? y2 : y3;
        A0 = fmaxf(A0, 0.0f);
        A1 = fmaxf(A1, 0.0f);

        float s = A0 + A1;
        #pragma unroll
        for (int off = 32; off >= 1; off >>= 1) s += __shfl_xor(s, off, 64);
        float mean = s * (1.0f / 128.0f);

        float d0 = A0 - mean, d1 = A1 - mean;
        float q = d0 * d0 + d1 * d1;
        #pragma unroll
        for (int off = 32; off >= 1; off >>= 1) q += __shfl_xor(q, off, 64);
        float rstd = rsqrtf(q * (1.0f / 128.0f) + LN_EPS);

        size_t rowp = (size_t)r * DIM;
        out[rowp + lane]      = d0 * sc0 * rstd + of0;
        out[rowp + lane + 64] = d1 * sc1 * rstd + of1;
    }
}

extern "C" void kernel_launch(void* const* d_in, const int* in_sizes, int n_in,
                              void* d_out, int out_size, void* d_ws, size_t ws_size,
                              hipStream_t stream) {
    const float* feat_in = (const float*)d_in[0];
    const int*   rows    = (const int*)d_in[1];
    const int*   cols    = (const int*)d_in[2];
    const float* vals    = (const float*)d_in[3];
    const float* W       = (const float*)d_in[4];
    const float* bias    = (const float*)d_in[5];
    const float* scale   = (const float*)d_in[6];
    const float* offset  = (const float*)d_in[7];
    float* out = (float*)d_out;

    // ---- workspace layout ----
    char* p = (char*)d_ws;
    int2* perm = (int2*)p;                 p += (size_t)SB * EPB * 8;        // 12.8 MB
    uint* tab  = (uint*)p;                 p += (size_t)SB * N_GROUPS * 4;   // 1.2 MB
    unsigned short* featb = (unsigned short*)p;
                                           p += (size_t)N_NODES * DIM * 2;   // 12.8 MB
    uint* wpk = (uint*)p;                  p += 32768;                       // 32 KB

    convert_pack<<<3126, 256, 0, stream>>>(feat_in, W, (uint*)featb, wpk);
    scatter<<<SB, 1024, 0, stream>>>(rows, cols, vals, perm, tab);
    agg_fused<<<N_GROUPS, 512, 0, stream>>>(perm, tab, featb,
                                            (const uint4*)wpk,
                                            bias, scale, offset, out);
}

// Round 15
// 181.400 us; speedup vs baseline: 1.1724x; 1.1724x over previous
//
#include <hip/hip_runtime.h>

typedef unsigned int uint;
typedef unsigned short ushort;
typedef __attribute__((ext_vector_type(8))) short short8;   // 8 bf16 = 4 VGPRs
typedef __attribute__((ext_vector_type(4))) float floatx4;  // MFMA C/D

#define N_NODES 50000
#define N_EDGES 1600000
#define DIM 128
#define LN_EPS 1e-10f

#define ROWS_PER_BUCKET 64
#define N_BUCKETS 782            // ceil(50000/64)
#define BUCKET_CAP 2560          // mean 2048, +11 sigma
#define EPB 8192                 // edges per scatter block
#define SB 196                   // scatter blocks
#define FCB 1563                 // feat-convert blocks (1024 thr, 1 float4 each)
#define GPAD 16                  // gcnt stride in ints (64 B/counter)
#define CAPR 76                  // per-row agg list slots (mean 32, +11 sigma)

__device__ __forceinline__ uint f2bf(float x) {
    uint u = __float_as_uint(x);
    return (u + 0x7FFFu + ((u >> 16) & 1u)) >> 16;   // RNE to bf16
}

// ---------------------------------------------------------------------------
// prep (R10 structure -- best measured): scatter blocks [0,SB) + convert
// blocks + W-pack block fused so convert fills CUs idled by scatter.
// Scatter: LDS histogram -> padded global atomic reservation -> staged-by-
// bucket LDS -> clustered perm writes.  W packed as bf16 row-major (MFMA B).
// ---------------------------------------------------------------------------
__global__ __launch_bounds__(1024) void prep(
    const float* __restrict__ feat, const float* __restrict__ W,
    const int* __restrict__ rows, const int* __restrict__ cols,
    const float* __restrict__ vals, int* __restrict__ gcnt,
    int2* __restrict__ perm, uint* __restrict__ featb_u,
    ushort* __restrict__ wbf)
{
    __shared__ int  cnt[N_BUCKETS];
    __shared__ int  gbase[N_BUCKETS];
    __shared__ int  lcur[N_BUCKETS];
    __shared__ int  csum[64];
    __shared__ int2 stageE[EPB];        // 64 KB
    const int bx = blockIdx.x;
    const int t  = threadIdx.x;

    if (bx >= SB) {
        int cb = bx - SB;
        if (cb < FCB) {                 // feat fp32 -> packed bf16
            int i = cb * 1024 + t;
            if (i < N_NODES * DIM / 4) {
                float4 v = ((const float4*)feat)[i];
                ((uint2*)featb_u)[i] = make_uint2(
                    f2bf(v.x) | (f2bf(v.y) << 16),
                    f2bf(v.z) | (f2bf(v.w) << 16));
            }
        } else {                        // W -> bf16 row-major (one block)
            for (int idx = t; idx < DIM * DIM; idx += 1024)
                wbf[idx] = (ushort)f2bf(W[idx]);
        }
        return;
    }

    // ---- phase A: histogram ----
    for (int i = t; i < N_BUCKETS; i += 1024) cnt[i] = 0;
    __syncthreads();
    const int base = bx * EPB;
    for (int k = 0; k < EPB; k += 1024) {
        int e = base + k + t;
        if (e < N_EDGES) atomicAdd(&cnt[rows[e] >> 6], 1);
    }
    __syncthreads();

    // ---- phase B: global reservation + LDS exclusive scan (64x13) ----
    for (int i = t; i < N_BUCKETS; i += 1024) {
        int c = cnt[i];
        gbase[i] = c ? atomicAdd(&gcnt[i * GPAD], c) : 0;
    }
    if (t < 64) {
        int s = 0;
        for (int j = 0; j < 13; ++j) {
            int idx = t * 13 + j;
            if (idx < N_BUCKETS) s += cnt[idx];
        }
        csum[t] = s;
    }
    __syncthreads();
    if (t == 0) {
        int s = 0;
        for (int i = 0; i < 64; ++i) { int c = csum[i]; csum[i] = s; s += c; }
    }
    __syncthreads();
    if (t < 64) {
        int run = csum[t];
        for (int j = 0; j < 13; ++j) {
            int idx = t * 13 + j;
            if (idx < N_BUCKETS) { lcur[idx] = run; run += cnt[idx]; }
        }
    }
    __syncthreads();

    // ---- phase C: stage entries grouped by bucket ----
    for (int k = 0; k < EPB; k += 1024) {
        int e = base + k + t;
        if (e < N_EDGES) {
            int r = rows[e];
            int b = r >> 6;
            int pos = atomicAdd(&lcur[b], 1);
            stageE[pos] = make_int2(
                (uint)cols[e] | ((uint)(r & 63) << 16) | ((uint)b << 22),
                __float_as_int(vals[e]));
        }
    }
    __syncthreads();

    // ---- phase D: clustered flush (slot order == destination order) ----
    int total = lcur[N_BUCKETS - 1];
    for (int k = 0; k < EPB; k += 1024) {
        int j = k + t;
        if (j < total) {
            int2 p = stageE[j];
            uint b = ((uint)p.x) >> 22;
            int lb = lcur[b] - cnt[b];
            int pos = gbase[b] + (j - lb);
            if (pos < BUCKET_CAP)       // statistically impossible; safety
                perm[(size_t)b * BUCKET_CAP + pos] = p;   // agg masks b bits
        }
    }
}

// ---------------------------------------------------------------------------
// agg_fused: 2 blocks per bucket (512 thr, 32 rows each; grid 1564).
// P1: compact own 32 rows into per-row LDS lists.
// P2: 4 rows/wave, bf16 gathers (lane holds feat elems 2*lane, 2*lane+1).
// P3: rows -> LDS bf16 stride 136; PACKED uint write at word index `lane`
//     (elems 2*lane|2*lane+1 -- R14's bug was writing lane/lane+64: a
//     K-permutation of A that scrambled the GEMM).
// P4: 128x128 linear via MFMA 16x16x32 bf16 (8 waves x 2 M-tiles x 4 K-steps;
//     B-frags from global bf16 W, L2-hot).
// P5: C+bias -> LDS, ReLU + LN + scale/offset -> out.
// ---------------------------------------------------------------------------
__global__ __launch_bounds__(512, 6) void agg_fused(
    const int2* __restrict__ perm, const int* __restrict__ gcnt,
    const ushort* __restrict__ featb, const ushort* __restrict__ wbf,
    const float* __restrict__ bias, const float* __restrict__ scale,
    const float* __restrict__ offset, float* __restrict__ out)
{
    __shared__ int2 lists[32 * CAPR];    // 19456 B union:
    ushort* rowsbuf = (ushort*)lists;    //   P3/P4: 32 x 136 bf16 (8704 B)
    float*  Cbuf    = (float*)lists;     //   P5:    32 x 132 fp32 (16896 B)
    __shared__ int  lcnt[32];

    const int t = threadIdx.x;
    const int b  = blockIdx.x >> 1;
    const int lo = (blockIdx.x & 1) * 32;
    if (t < 32) lcnt[t] = 0;
    __syncthreads();

    int n = gcnt[b * GPAD];
    if (n > BUCKET_CAP) n = BUCKET_CAP;
    const int2* pb = perm + (size_t)b * BUCKET_CAP;

    // ---- P1: compaction ----
    for (int e = t; e < n; e += 512) {
        int2 p = pb[e];
        int rl = ((p.x >> 16) & 63) - lo;
        if ((uint)rl < 32u) {
            int pos = atomicAdd(&lcnt[rl], 1);
            if (pos < CAPR)
                lists[rl * CAPR + pos] = make_int2(p.x & 0xFFFF, p.y);
        }
    }
    __syncthreads();

    const int lane = t & 63;
    const int wid  = t >> 6;        // 0..7
    const int rb   = wid * 4;       // this wave's first local row

    // ---- P2: gather + accumulate (ax = elem 2*lane, ay = elem 2*lane+1) ----
    float ax[4], ay[4];
    #pragma unroll
    for (int j = 0; j < 4; ++j) {
        int rl = rb + j;
        int cnt = lcnt[rl];
        if (cnt > CAPR) cnt = CAPR;
        const int2* L = &lists[rl * CAPR];
        float sx = 0.f, sy = 0.f;
        int e = 0;
        for (; e + 7 < cnt; e += 8) {
            int2 p[8]; uint g[8];
            #pragma unroll
            for (int k = 0; k < 8; ++k) p[k] = L[e + k];
            #pragma unroll
            for (int k = 0; k < 8; ++k)
                g[k] = ((const uint*)(featb + (size_t)p[k].x * DIM))[lane];
            #pragma unroll
            for (int k = 0; k < 8; ++k) {
                float v = __int_as_float(p[k].y);
                sx = fmaf(v, __uint_as_float(g[k] << 16), sx);
                sy = fmaf(v, __uint_as_float(g[k] & 0xFFFF0000u), sy);
            }
        }
        for (; e < cnt; ++e) {
            int2 p = L[e];
            uint g = ((const uint*)(featb + (size_t)p.x * DIM))[lane];
            float v = __int_as_float(p.y);
            sx = fmaf(v, __uint_as_float(g << 16), sx);
            sy = fmaf(v, __uint_as_float(g & 0xFFFF0000u), sy);
        }
        ax[j] = sx; ay[j] = sy;
    }
    __syncthreads();               // lists dead

    // ---- P3: rows -> LDS bf16 (TRUE element order: word `lane` holds
    //          elems 2*lane, 2*lane+1), stride 136 ushorts ----
    #pragma unroll
    for (int j = 0; j < 4; ++j) {
        uint pk = f2bf(ax[j]) | (f2bf(ay[j]) << 16);
        *(uint*)&rowsbuf[(rb + j) * 136 + 2 * lane] = pk;
    }
    __syncthreads();

    // ---- P4: MFMA GEMM.  D[m][n] = sum_k A[m][k] * W[n][k] ----
    const int l15  = lane & 15;
    const int quad = lane >> 4;
    const int n0   = wid * 16 + l15;       // this wave's N-column
    const float bb = bias[n0];

    floatx4 acc0 = {0.f, 0.f, 0.f, 0.f};   // m-tile 0 (rows 0..15)
    floatx4 acc1 = {0.f, 0.f, 0.f, 0.f};   // m-tile 1 (rows 16..31)
    #pragma unroll
    for (int kt = 0; kt < 4; ++kt) {
        int k0 = kt * 32 + quad * 8;
        short8 af0 = *(const short8*)&rowsbuf[l15 * 136 + k0];
        short8 af1 = *(const short8*)&rowsbuf[(l15 + 16) * 136 + k0];
        short8 bf  = *(const short8*)&wbf[n0 * DIM + k0];   // B[k][n]=W[n][k]
        acc0 = __builtin_amdgcn_mfma_f32_16x16x32_bf16(af0, bf, acc0, 0, 0, 0);
        acc1 = __builtin_amdgcn_mfma_f32_16x16x32_bf16(af1, bf, acc1, 0, 0, 0);
    }
    __syncthreads();               // rowsbuf dead

    // C/D layout: lane holds D[m=quad*4+r][n=l15] -> stage to Cbuf (+bias)
    #pragma unroll
    for (int r = 0; r < 4; ++r) {
        int m = quad * 4 + r;
        Cbuf[m * 132 + n0]        = acc0[r] + bb;
        Cbuf[(m + 16) * 132 + n0] = acc1[r] + bb;
    }
    __syncthreads();

    // ---- P5: ReLU + LN + scale/offset -> out (4 rows per wave) ----
    const float sc0 = scale[lane],  sc1 = scale[lane + 64];
    const float of0 = offset[lane], of1 = offset[lane + 64];

    #pragma unroll
    for (int j = 0; j < 4; ++j) {
        int rl = rb + j;
        int r  = b * ROWS_PER_BUCKET + lo + rl;
        if (r >= N_NODES) continue;                       // wave-uniform
        float A0 = fmaxf(Cbuf[rl * 132 + lane],      0.0f);
        float A1 = fmaxf(Cbuf[rl * 132 + lane + 64], 0.0f);

        float s = A0 + A1;
        #pragma unroll
        for (int off = 32; off >= 1; off >>= 1) s += __shfl_xor(s, off, 64);
        float mean = s * (1.0f / 128.0f);

        float d0 = A0 - mean, d1 = A1 - mean;
        float q = d0 * d0 + d1 * d1;
        #pragma unroll
        for (int off = 32; off >= 1; off >>= 1) q += __shfl_xor(q, off, 64);
        float rstd = rsqrtf(q * (1.0f / 128.0f) + LN_EPS);

        size_t rowp = (size_t)r * DIM;
        out[rowp + lane]      = d0 * sc0 * rstd + of0;
        out[rowp + lane + 64] = d1 * sc1 * rstd + of1;
    }
}

extern "C" void kernel_launch(void* const* d_in, const int* in_sizes, int n_in,
                              void* d_out, int out_size, void* d_ws, size_t ws_size,
                              hipStream_t stream) {
    const float* feat_in = (const float*)d_in[0];
    const int*   rows    = (const int*)d_in[1];
    const int*   cols    = (const int*)d_in[2];
    const float* vals    = (const float*)d_in[3];
    const float* W       = (const float*)d_in[4];
    const float* bias    = (const float*)d_in[5];
    const float* scale   = (const float*)d_in[6];
    const float* offset  = (const float*)d_in[7];
    float* out = (float*)d_out;

    // ---- workspace layout ----
    char* p = (char*)d_ws;
    int2* perm = (int2*)p;                 p += (size_t)N_BUCKETS * BUCKET_CAP * 8; // 16.0 MB
    ushort* featb = (ushort*)p;            p += (size_t)N_NODES * DIM * 2;          // 12.8 MB
    ushort* wbf = (ushort*)p;              p += DIM * DIM * 2;                      // 32 KB
    int*  gcnt = (int*)p;                  p += (size_t)N_BUCKETS * GPAD * 4;       // 50 KB padded

    hipMemsetAsync(gcnt, 0, (size_t)N_BUCKETS * GPAD * sizeof(int), stream);

    prep<<<SB + FCB + 1, 1024, 0, stream>>>(feat_in, W, rows, cols, vals,
                                            gcnt, perm, (uint*)featb, wbf);
    agg_fused<<<N_BUCKETS * 2, 512, 0, stream>>>(perm, gcnt, featb, wbf,
                                                 bias, scale, offset, out);
}